// Round 2
// baseline (615.414 us; speedup 1.0000x reference)
//
#include <hip/hip_runtime.h>
#include <hip/hip_bf16.h>

typedef unsigned short ush;
typedef __bf16 v8bf __attribute__((ext_vector_type(8)));
typedef float f32x4 __attribute__((ext_vector_type(4)));

#define SPD 56           // input spatial dim
#define OSD 52           // output spatial dim
#define SP3 175616       // 56^3
#define N_A_ELEMS (2*125*64*32)   // 512000

// ---------------- kernel 1: build fused conv kernel A[cg][tau][o][c] (bf16) -------------
__global__ void build_A(const float* __restrict__ weight, const float* __restrict__ w_sc0,
                        const float* __restrict__ w_sc1, ush* __restrict__ A) {
    int f = blockIdx.x * 256 + threadIdx.x;
    if (f >= N_A_ELEMS) return;
    int c   = f & 31;
    int o   = (f >> 5) & 63;
    int t2  = f >> 11;            // cg*125 + tau
    int tau = t2 % 125;
    int cg  = t2 / 125;
    int i   = cg * 32 + c;        // input channel
    int dz = tau / 25, dy = (tau / 5) % 5, dx = tau % 5;
    float rz = -1.f + 0.5f * dz, ry = -1.f + 0.5f * dy, rx = -1.f + 0.5f * dx;
    float d = sqrtf(rz * rz + ry * ry + rx * rx);
    float dm = fmaxf(d, 1e-12f);
    float nv[3] = { rz / dm, ry / dm, rx / dm };
    float emb[5];
    #pragma unroll
    for (int m = 0; m < 5; m++) {
        float diff = 4.f * d - (float)m;
        float ta = diff + 1.f, tb = 1.f - diff;
        float sa = ta > 0.f ? expf(-1.f / ta) : 0.f;
        float sb = tb > 0.f ? expf(-1.f / tb) : 0.f;
        emb[m] = 1.14136f * 7.3890560989306495f * sa * sb;
    }
    const float PW0 = 0.17677669529663687f;  // sqrt(1/32)
    const float PW1 = 0.30618621784789724f;  // sqrt(3/32)
    const float IS3 = 0.57735026918962576f;  // 1/sqrt(3)
    float val = 0.f;
    int widx = -1; float scale = 0.f;
    if (i < 16) {
        if (o < 16) { widx = i * 16 + o;                         scale = PW0; }
        else        { int wc = (o - 16) / 3, kc = (o - 16) % 3;
                      widx = 256 + i * 16 + wc;                  scale = PW1 * nv[kc]; }
    } else {
        int u = (i - 16) / 3, ic = (i - 16) % 3;
        if (o < 16) { widx = 768 + u * 16 + o;                   scale = PW0 * nv[ic]; }
        else        { int wc = (o - 16) / 3, jc = (o - 16) % 3;
                      if (ic == jc) { widx = 512 + u * 16 + wc;  scale = PW1 * IS3; } }
    }
    if (widx >= 0) {
        float wv = 0.f;
        #pragma unroll
        for (int m = 0; m < 5; m++) wv += emb[m] * weight[m * 1024 + widx];
        val = scale * wv;
    }
    if (tau == 62) {  // center tap: fold sc (pointwise map, inv = 1/sqrt(16) = 0.25)
        if (i < 16 && o < 16) val += 0.25f * w_sc0[i * 16 + o];
        else if (i >= 16 && o >= 16) {
            int u = (i - 16) / 3, ic = (i - 16) % 3;
            int wc = (o - 16) / 3, jc = (o - 16) % 3;
            if (ic == jc) val += 0.25f * w_sc1[u * 16 + wc];
        }
    }
    __hip_bfloat16 b = __float2bfloat16(val);
    A[f] = *(ush*)&b;
}

// ---------------- kernel 2: x fp32 [c64][s] -> bf16 [cg2][s][c32], LDS transpose -------
// grid (2744, 2): 64 spatial positions x 32 channels per block
__global__ void conv_x(const float* __restrict__ x, ush* __restrict__ xb) {
    __shared__ float t[64 * 33];
    const int tid = threadIdx.x;
    const int s0 = blockIdx.x * 64;
    const int cg = blockIdx.y;
    const int w = tid >> 6, l = tid & 63;
    // phase 1: coalesced reads (64 consecutive floats per channel), transposed LDS write
    #pragma unroll
    for (int k = 0; k < 8; k++) {
        int c = w * 8 + k;
        t[l * 33 + c] = x[(cg * 32 + c) * SP3 + s0 + l];
    }
    __syncthreads();
    // phase 2: each thread packs 8 channels of one voxel -> one 16B write (coalesced)
    int v = tid >> 2, qq = tid & 3;
    union { ush u[8]; uint4 q4; } pk;
    #pragma unroll
    for (int j = 0; j < 8; j++) {
        __hip_bfloat16 b = __float2bfloat16(t[v * 33 + qq * 8 + j]);
        pk.u[j] = *(ush*)&b;
    }
    *(uint4*)(xb + ((size_t)(cg * SP3 + s0 + v)) * 32 + qq * 8) = pk.q4;
}

// ---------------- kernel 3: main conv ---------------------------------------------------
// grid (13,13,13); block 64 = ONE wave owning the full 64px x 64outch tile.
// patch: 8x8x8 voxels x 32ch (one cg) in LDS, XOR-swizzled chunk layout, 32 KB.
__launch_bounds__(64, 1)
__global__ void conv_main(const ush* __restrict__ A, const ush* __restrict__ xb,
                          float* __restrict__ out) {
    __shared__ ush patch[512 * 32];   // 32768 B, no padding (swizzled)

    const int lane = threadIdx.x;
    const int n    = lane & 15;
    const int q    = lane >> 4;
    const int x0 = blockIdx.x * 4, y0 = blockIdx.y * 4, z0 = blockIdx.z * 4;

    // pixel p = nt*16 + n -> (z=nt, y=n>>2, x=n&3); patch voxel index = z*64 + y*8 + x
    const int rbase = ((n >> 2) << 3) + (n & 3);

    f32x4 acc[4][4];
    #pragma unroll
    for (int mt = 0; mt < 4; mt++)
        #pragma unroll
        for (int nt = 0; nt < 4; nt++) {
            f32x4 z = {0.f, 0.f, 0.f, 0.f};
            acc[mt][nt] = z;
        }

    for (int cg = 0; cg < 2; cg++) {
        __syncthreads();
        // stage 512 voxels x 32ch: 2048 16B-units, 32 per thread, swizzled LDS slots
        #pragma unroll 8
        for (int it = 0; it < 32; it++) {
            int u   = lane + it * 64;
            int qq  = u & 3;
            int vox = u >> 2;
            int xp = vox & 7, yp = (vox >> 3) & 7, zp = vox >> 6;
            const ush* g = xb + ((size_t)((cg * SPD + z0 + zp) * SPD + (y0 + yp)) * SPD + (x0 + xp)) * 32 + qq * 8;
            uint4 v = *(const uint4*)g;
            int slot = vox * 4 + ((qq + vox + (vox >> 3)) & 3);
            *(uint4*)(patch + slot * 8) = v;
        }
        __syncthreads();

        const ush* Ap = A + cg * 125 * 2048 + n * 32 + q * 8;
        for (int dz = 0; dz < 5; dz++)
            for (int dy = 0; dy < 5; dy++) {
                int rb2 = rbase + dz * 64 + dy * 8;
                #pragma unroll
                for (int dx = 0; dx < 5; dx++) {
                    v8bf a[4];
                    #pragma unroll
                    for (int mt = 0; mt < 4; mt++)
                        a[mt] = *(const v8bf*)(Ap + mt * 512);
                    Ap += 2048;
                    v8bf b[4];
                    #pragma unroll
                    for (int nt = 0; nt < 4; nt++) {
                        int r = rb2 + dx + nt * 64;
                        int slot = r * 4 + ((q + r + (r >> 3)) & 3);
                        b[nt] = *(const v8bf*)(patch + slot * 8);
                    }
                    #pragma unroll
                    for (int mt = 0; mt < 4; mt++)
                        #pragma unroll
                        for (int nt = 0; nt < 4; nt++)
                            acc[mt][nt] = __builtin_amdgcn_mfma_f32_16x16x32_bf16(a[mt], b[nt], acc[mt][nt], 0, 0, 0);
                }
            }
    }

    // store: D row m = q*4 + r -> out-ch, col = n -> pixel
    #pragma unroll
    for (int mt = 0; mt < 4; mt++)
        #pragma unroll
        for (int nt = 0; nt < 4; nt++)
            #pragma unroll
            for (int r = 0; r < 4; r++) {
                int o  = mt * 16 + q * 4 + r;
                int zz = z0 + nt, yy = y0 + (n >> 2), xx = x0 + (n & 3);
                out[((o * OSD + zz) * OSD + yy) * OSD + xx] = acc[mt][nt][r];
            }
}

extern "C" void kernel_launch(void* const* d_in, const int* in_sizes, int n_in,
                              void* d_out, int out_size, void* d_ws, size_t ws_size,
                              hipStream_t stream) {
    const float* x      = (const float*)d_in[0];
    const float* weight = (const float*)d_in[1];
    const float* w_sc0  = (const float*)d_in[2];
    const float* w_sc1  = (const float*)d_in[3];
    float* out = (float*)d_out;

    ush* A  = (ush*)d_ws;                               // 1,024,000 B
    ush* xb = (ush*)((char*)d_ws + (1 << 20));          // 22.5 MB

    build_A<<<N_A_ELEMS / 256, 256, 0, stream>>>(weight, w_sc0, w_sc1, A);
    dim3 gx(SP3 / 64, 2, 1);
    conv_x<<<gx, 256, 0, stream>>>(x, xb);
    dim3 grid(13, 13, 13);
    conv_main<<<grid, 64, 0, stream>>>(A, xb, out);
}

// Round 3
// 289.196 us; speedup vs baseline: 2.1280x; 2.1280x over previous
//
#include <hip/hip_runtime.h>
#include <hip/hip_bf16.h>

typedef unsigned short ush;
typedef __bf16 v8bf __attribute__((ext_vector_type(8)));
typedef float f32x4 __attribute__((ext_vector_type(4)));

#define SPD 56           // input spatial dim
#define OSD 52           // output spatial dim
#define SP3 175616       // 56^3
#define N_A_ELEMS (2*125*64*32)   // 512000

// ---------------- kernel 1: build fused conv kernel A[cg][tau][o][c] (bf16) -------------
__global__ void build_A(const float* __restrict__ weight, const float* __restrict__ w_sc0,
                        const float* __restrict__ w_sc1, ush* __restrict__ A) {
    int f = blockIdx.x * 256 + threadIdx.x;
    if (f >= N_A_ELEMS) return;
    int c   = f & 31;
    int o   = (f >> 5) & 63;
    int t2  = f >> 11;            // cg*125 + tau
    int tau = t2 % 125;
    int cg  = t2 / 125;
    int i   = cg * 32 + c;        // input channel
    int dz = tau / 25, dy = (tau / 5) % 5, dx = tau % 5;
    float rz = -1.f + 0.5f * dz, ry = -1.f + 0.5f * dy, rx = -1.f + 0.5f * dx;
    float d = sqrtf(rz * rz + ry * ry + rx * rx);
    float dm = fmaxf(d, 1e-12f);
    float nv[3] = { rz / dm, ry / dm, rx / dm };
    float emb[5];
    #pragma unroll
    for (int m = 0; m < 5; m++) {
        float diff = 4.f * d - (float)m;
        float ta = diff + 1.f, tb = 1.f - diff;
        float sa = ta > 0.f ? expf(-1.f / ta) : 0.f;
        float sb = tb > 0.f ? expf(-1.f / tb) : 0.f;
        emb[m] = 1.14136f * 7.3890560989306495f * sa * sb;
    }
    const float PW0 = 0.17677669529663687f;  // sqrt(1/32)
    const float PW1 = 0.30618621784789724f;  // sqrt(3/32)
    const float IS3 = 0.57735026918962576f;  // 1/sqrt(3)
    float val = 0.f;
    int widx = -1; float scale = 0.f;
    if (i < 16) {
        if (o < 16) { widx = i * 16 + o;                         scale = PW0; }
        else        { int wc = (o - 16) / 3, kc = (o - 16) % 3;
                      widx = 256 + i * 16 + wc;                  scale = PW1 * nv[kc]; }
    } else {
        int u = (i - 16) / 3, ic = (i - 16) % 3;
        if (o < 16) { widx = 768 + u * 16 + o;                   scale = PW0 * nv[ic]; }
        else        { int wc = (o - 16) / 3, jc = (o - 16) % 3;
                      if (ic == jc) { widx = 512 + u * 16 + wc;  scale = PW1 * IS3; } }
    }
    if (widx >= 0) {
        float wv = 0.f;
        #pragma unroll
        for (int m = 0; m < 5; m++) wv += emb[m] * weight[m * 1024 + widx];
        val = scale * wv;
    }
    if (tau == 62) {  // center tap: fold sc (pointwise map, inv = 1/sqrt(16) = 0.25)
        if (i < 16 && o < 16) val += 0.25f * w_sc0[i * 16 + o];
        else if (i >= 16 && o >= 16) {
            int u = (i - 16) / 3, ic = (i - 16) % 3;
            int wc = (o - 16) / 3, jc = (o - 16) % 3;
            if (ic == jc) val += 0.25f * w_sc1[u * 16 + wc];
        }
    }
    __hip_bfloat16 b = __float2bfloat16(val);
    A[f] = *(ush*)&b;
}

// ---------------- kernel 2: x fp32 [c64][s] -> bf16 [cg2][s][c32], LDS transpose -------
__global__ void conv_x(const float* __restrict__ x, ush* __restrict__ xb) {
    __shared__ float t[64 * 33];
    const int tid = threadIdx.x;
    const int s0 = blockIdx.x * 64;
    const int cg = blockIdx.y;
    const int w = tid >> 6, l = tid & 63;
    #pragma unroll
    for (int k = 0; k < 8; k++) {
        int c = w * 8 + k;
        t[l * 33 + c] = x[(cg * 32 + c) * SP3 + s0 + l];
    }
    __syncthreads();
    int v = tid >> 2, qq = tid & 3;
    union { ush u[8]; uint4 q4; } pk;
    #pragma unroll
    for (int j = 0; j < 8; j++) {
        __hip_bfloat16 b = __float2bfloat16(t[v * 33 + qq * 8 + j]);
        pk.u[j] = *(ush*)&b;
    }
    *(uint4*)(xb + ((size_t)(cg * SP3 + s0 + v)) * 32 + qq * 8) = pk.q4;
}

// ---------------- kernel 3: main conv ---------------------------------------------------
// grid (13,13,13); block 256 = 4 waves. Every wave owns the FULL 64px x 64oc tile;
// K (250 flat taps = cg*125+tau) is split across the 4 waves; LDS tree-reduce at end.
// patch: both cgs, 8x8x8 vox x 32ch each = 4096 16B-chunks = 64 KB, XOR-swizzled.
__launch_bounds__(256, 2)
__global__ void conv_main(const ush* __restrict__ A, const ush* __restrict__ xb,
                          float* __restrict__ out) {
    __shared__ ush patch[4096 * 8];   // 65536 B (reused as f32 for reduction)

    const int tid  = threadIdx.x;
    const int wv   = tid >> 6;
    const int lane = tid & 63;
    const int n    = lane & 15;
    const int q    = lane >> 4;
    const int x0 = blockIdx.x * 4, y0 = blockIdx.y * 4, z0 = blockIdx.z * 4;

    // pixel p = nt*16 + n -> (z=nt, y=n>>2, x=n&3); patch voxel = z*64 + y*8 + x
    const int rbase = ((n >> 2) << 3) + (n & 3);

    // ---- stage both channel-groups: 4096 chunks, 16 per thread, swizzled slots ----
    #pragma unroll 4
    for (int it = 0; it < 16; it++) {
        int u   = tid + it * 256;
        int qq  = u & 3;
        int vf  = u >> 2;                 // cg*512 + vox
        int cg  = vf >> 9;
        int vox = vf & 511;
        int xp = vox & 7, yp = (vox >> 3) & 7, zp = vox >> 6;
        const ush* g = xb + ((size_t)((cg * SPD + z0 + zp) * SPD + (y0 + yp)) * SPD + (x0 + xp)) * 32 + qq * 8;
        uint4 v = *(const uint4*)g;
        int slot = vf * 4 + ((qq + vf + (vf >> 3)) & 3);
        *(uint4*)(patch + slot * 8) = v;
    }
    __syncthreads();

    f32x4 acc[4][4];
    #pragma unroll
    for (int mt = 0; mt < 4; mt++)
        #pragma unroll
        for (int nt = 0; nt < 4; nt++) {
            f32x4 z = {0.f, 0.f, 0.f, 0.f};
            acc[mt][nt] = z;
        }

    // ---- K-split main loop: wave wv handles flat taps [t0, t1) ----
    const int t0 = (wv * 250) >> 2;          // 0, 62, 125, 187
    const int t1 = ((wv + 1) * 250) >> 2;    // 62, 125, 187, 250

    const ush* Ap = A + (size_t)t0 * 2048 + n * 32 + q * 8;
    v8bf a[4];
    #pragma unroll
    for (int mt = 0; mt < 4; mt++) a[mt] = *(const v8bf*)(Ap + mt * 512);

    for (int t = t0; t < t1; t++) {
        int tt = t, cg = 0;
        if (tt >= 125) { cg = 1; tt -= 125; }
        int dz = tt / 25;
        int r2 = tt - dz * 25;
        int dy = r2 / 5;
        int dx = r2 - dy * 5;
        int v0 = cg * 512 + dz * 64 + dy * 8 + dx + rbase;      // nt=0 voxel
        int slot0 = v0 * 4 + ((q + v0 + (v0 >> 3)) & 3);        // perm invariant in nt

        v8bf b[4];
        #pragma unroll
        for (int nt = 0; nt < 4; nt++)
            b[nt] = *(const v8bf*)(patch + slot0 * 8 + nt * 2048);

        v8bf anx[4];   // prefetch next tap's A (safe: reads stay inside d_ws)
        #pragma unroll
        for (int mt = 0; mt < 4; mt++) anx[mt] = *(const v8bf*)(Ap + 2048 + mt * 512);

        #pragma unroll
        for (int mt = 0; mt < 4; mt++)
            #pragma unroll
            for (int nt = 0; nt < 4; nt++)
                acc[mt][nt] = __builtin_amdgcn_mfma_f32_16x16x32_bf16(a[mt], b[nt], acc[mt][nt], 0, 0, 0);

        #pragma unroll
        for (int mt = 0; mt < 4; mt++) a[mt] = anx[mt];
        Ap += 2048;
    }

    // ---- cross-wave reduction in LDS: red[w][frag16][lane] ----
    __syncthreads();
    float* red = (float*)patch;
    #pragma unroll
    for (int mt = 0; mt < 4; mt++)
        #pragma unroll
        for (int nt = 0; nt < 4; nt++)
            *(f32x4*)(red + wv * 4096 + (mt * 4 + nt) * 256 + lane * 4) = acc[mt][nt];
    __syncthreads();

    // wave wv owns mt = wv: sum the 4 wave-copies, store
    #pragma unroll
    for (int nt = 0; nt < 4; nt++) {
        f32x4 s = *(const f32x4*)(red + 0 * 4096 + (wv * 4 + nt) * 256 + lane * 4);
        #pragma unroll
        for (int src = 1; src < 4; src++)
            s += *(const f32x4*)(red + src * 4096 + (wv * 4 + nt) * 256 + lane * 4);
        int zz = z0 + nt, yy = y0 + (n >> 2), xx = x0 + (n & 3);
        #pragma unroll
        for (int r = 0; r < 4; r++) {
            int o = wv * 16 + q * 4 + r;
            out[((o * OSD + zz) * OSD + yy) * OSD + xx] = s[r];
        }
    }
}

extern "C" void kernel_launch(void* const* d_in, const int* in_sizes, int n_in,
                              void* d_out, int out_size, void* d_ws, size_t ws_size,
                              hipStream_t stream) {
    const float* x      = (const float*)d_in[0];
    const float* weight = (const float*)d_in[1];
    const float* w_sc0  = (const float*)d_in[2];
    const float* w_sc1  = (const float*)d_in[3];
    float* out = (float*)d_out;

    ush* A  = (ush*)d_ws;                               // 1,024,000 B
    ush* xb = (ush*)((char*)d_ws + (1 << 20));          // 22.5 MB

    build_A<<<N_A_ELEMS / 256, 256, 0, stream>>>(weight, w_sc0, w_sc1, A);
    dim3 gx(SP3 / 64, 2, 1);
    conv_x<<<gx, 256, 0, stream>>>(x, xb);
    dim3 grid(13, 13, 13);
    conv_main<<<grid, 256, 0, stream>>>(A, xb, out);
}

// Round 4
// 264.625 us; speedup vs baseline: 2.3256x; 1.0929x over previous
//
#include <hip/hip_runtime.h>
#include <hip/hip_bf16.h>

typedef unsigned short ush;
typedef __bf16 v8bf __attribute__((ext_vector_type(8)));
typedef float f32x4 __attribute__((ext_vector_type(4)));

#define SPD 56           // input spatial dim
#define OSD 52           // output spatial dim
#define SP3 175616       // 56^3
#define N_A_ELEMS (2*125*64*32)   // 512000 (+2048 zero pad appended)

// ---------------- kernel 1: build fused conv kernel A[cg][tau][o][c] (bf16) -------------
__global__ void build_A(const float* __restrict__ weight, const float* __restrict__ w_sc0,
                        const float* __restrict__ w_sc1, ush* __restrict__ A) {
    int f = blockIdx.x * 256 + threadIdx.x;
    if (f >= N_A_ELEMS) {                 // zero tap slice for K-padding (taps 125..127)
        if (f < N_A_ELEMS + 2048) A[f] = 0;
        return;
    }
    int c   = f & 31;
    int o   = (f >> 5) & 63;
    int t2  = f >> 11;            // cg*125 + tau
    int tau = t2 % 125;
    int cg  = t2 / 125;
    int i   = cg * 32 + c;        // input channel
    int dz = tau / 25, dy = (tau / 5) % 5, dx = tau % 5;
    float rz = -1.f + 0.5f * dz, ry = -1.f + 0.5f * dy, rx = -1.f + 0.5f * dx;
    float d = sqrtf(rz * rz + ry * ry + rx * rx);
    float dm = fmaxf(d, 1e-12f);
    float nv[3] = { rz / dm, ry / dm, rx / dm };
    float emb[5];
    #pragma unroll
    for (int m = 0; m < 5; m++) {
        float diff = 4.f * d - (float)m;
        float ta = diff + 1.f, tb = 1.f - diff;
        float sa = ta > 0.f ? expf(-1.f / ta) : 0.f;
        float sb = tb > 0.f ? expf(-1.f / tb) : 0.f;
        emb[m] = 1.14136f * 7.3890560989306495f * sa * sb;
    }
    const float PW0 = 0.17677669529663687f;  // sqrt(1/32)
    const float PW1 = 0.30618621784789724f;  // sqrt(3/32)
    const float IS3 = 0.57735026918962576f;  // 1/sqrt(3)
    float val = 0.f;
    int widx = -1; float scale = 0.f;
    if (i < 16) {
        if (o < 16) { widx = i * 16 + o;                         scale = PW0; }
        else        { int wc = (o - 16) / 3, kc = (o - 16) % 3;
                      widx = 256 + i * 16 + wc;                  scale = PW1 * nv[kc]; }
    } else {
        int u = (i - 16) / 3, ic = (i - 16) % 3;
        if (o < 16) { widx = 768 + u * 16 + o;                   scale = PW0 * nv[ic]; }
        else        { int wc = (o - 16) / 3, jc = (o - 16) % 3;
                      if (ic == jc) { widx = 512 + u * 16 + wc;  scale = PW1 * IS3; } }
    }
    if (widx >= 0) {
        float wv = 0.f;
        #pragma unroll
        for (int m = 0; m < 5; m++) wv += emb[m] * weight[m * 1024 + widx];
        val = scale * wv;
    }
    if (tau == 62) {  // center tap: fold sc (pointwise map, inv = 1/sqrt(16) = 0.25)
        if (i < 16 && o < 16) val += 0.25f * w_sc0[i * 16 + o];
        else if (i >= 16 && o >= 16) {
            int u = (i - 16) / 3, ic = (i - 16) % 3;
            int wc = (o - 16) / 3, jc = (o - 16) % 3;
            if (ic == jc) val += 0.25f * w_sc1[u * 16 + wc];
        }
    }
    __hip_bfloat16 b = __float2bfloat16(val);
    A[f] = *(ush*)&b;
}

// ---------------- kernel 2: x fp32 [c64][s] -> bf16 [cg2][s][c32], LDS transpose -------
__global__ void conv_x(const float* __restrict__ x, ush* __restrict__ xb) {
    __shared__ float t[64 * 33];
    const int tid = threadIdx.x;
    const int s0 = blockIdx.x * 64;
    const int cg = blockIdx.y;
    const int w = tid >> 6, l = tid & 63;
    #pragma unroll
    for (int k = 0; k < 8; k++) {
        int c = w * 8 + k;
        t[l * 33 + c] = x[(cg * 32 + c) * SP3 + s0 + l];
    }
    __syncthreads();
    int v = tid >> 2, qq = tid & 3;
    union { ush u[8]; uint4 q4; } pk;
    #pragma unroll
    for (int j = 0; j < 8; j++) {
        __hip_bfloat16 b = __float2bfloat16(t[v * 33 + qq * 8 + j]);
        pk.u[j] = *(ush*)&b;
    }
    *(uint4*)(xb + ((size_t)(cg * SP3 + s0 + v)) * 32 + qq * 8) = pk.q4;
}

// ---------------- kernel 3: main conv ---------------------------------------------------
// grid (13,13,13); block 256 = 4 waves, each owning the FULL 64px x 64oc tile.
// Per channel-group: stage 8x8x8 vox x 32ch (32 KB, XOR-swizzled), K-split 128 taps
// (125 real + 3 zero-A pad) x 32 per wave, A+B software-pipelined one tap ahead.
__launch_bounds__(256, 3)
__global__ void conv_main(const ush* __restrict__ A, const ush* __restrict__ xb,
                          float* __restrict__ out) {
    __shared__ ush patch[2048 * 8];   // 32768 B; reused as f32 red[2][16][64][4]

    const int tid  = threadIdx.x;
    const int wv   = tid >> 6;
    const int lane = tid & 63;
    const int n    = lane & 15;
    const int q    = lane >> 4;
    const int x0 = blockIdx.x * 4, y0 = blockIdx.y * 4, z0 = blockIdx.z * 4;

    // pixel p = nt*16 + n -> (z=nt, y=n>>2, x=n&3); patch voxel = z*64 + y*8 + x
    const int rbase = ((n >> 2) << 3) + (n & 3);
    const ush* Aw = A + n * 32 + q * 8;

    f32x4 acc[4][4];
    #pragma unroll
    for (int mt = 0; mt < 4; mt++)
        #pragma unroll
        for (int nt = 0; nt < 4; nt++) {
            f32x4 z = {0.f, 0.f, 0.f, 0.f};
            acc[mt][nt] = z;
        }

    for (int cg = 0; cg < 2; cg++) {
        __syncthreads();
        // stage this cg: 2048 16B-chunks, 8 per thread, XOR-swizzled slots
        #pragma unroll 4
        for (int it = 0; it < 8; it++) {
            int u   = tid + it * 256;
            int qq  = u & 3;
            int vox = u >> 2;
            int xp = vox & 7, yp = (vox >> 3) & 7, zp = vox >> 6;
            const ush* g = xb + ((size_t)((cg * SPD + z0 + zp) * SPD + (y0 + yp)) * SPD + (x0 + xp)) * 32 + qq * 8;
            uint4 v = *(const uint4*)g;
            int slot = vox * 4 + ((qq + vox + (vox >> 3)) & 3);
            *(uint4*)(patch + slot * 8) = v;
        }
        __syncthreads();

        // ---- K-split: wave wv owns taps [wv*32, wv*32+32); taps >=125 have zero A ----
        const int t0 = wv * 32;
        int dz = t0 / 25; int rr = t0 - dz * 25; int dy = rr / 5; int dx = rr - dy * 5;
        int vb = dz * 64 + dy * 8 + dx;
        int v0 = vb + rbase;
        int slot0 = v0 * 4 + ((q + v0 + (v0 >> 3)) & 3);

        v8bf bc[4], ac[4];
        #pragma unroll
        for (int nt = 0; nt < 4; nt++)
            bc[nt] = *(const v8bf*)(patch + slot0 * 8 + nt * 2048);
        {
            int toff = cg * 125 + t0;
            #pragma unroll
            for (int mt = 0; mt < 4; mt++)
                ac[mt] = *(const v8bf*)(Aw + (size_t)toff * 2048 + mt * 512);
        }

        #pragma unroll 2
        for (int j = 0; j < 32; j++) {
            // advance decode to tap t0+j+1
            int c1 = (dx == 4);
            dx = c1 ? 0 : dx + 1;
            int c2 = c1 & (dy == 4);
            dy = c2 ? 0 : dy + c1;
            dz += c2;
            int vbn = dz * 64 + dy * 8 + dx;
            int vbs = (vbn > 292) ? 0 : vbn;          // clamp pad taps in-bounds
            int v1 = vbs + rbase;
            int slot1 = v1 * 4 + ((q + v1 + (v1 >> 3)) & 3);

            v8bf bn[4];
            #pragma unroll
            for (int nt = 0; nt < 4; nt++)
                bn[nt] = *(const v8bf*)(patch + slot1 * 8 + nt * 2048);

            int tn = t0 + j + 1;
            int toffn = (tn < 125) ? (cg * 125 + tn) : 250;   // 250 -> zero slice
            v8bf an[4];
            #pragma unroll
            for (int mt = 0; mt < 4; mt++)
                an[mt] = *(const v8bf*)(Aw + (size_t)toffn * 2048 + mt * 512);

            #pragma unroll
            for (int mt = 0; mt < 4; mt++)
                #pragma unroll
                for (int nt = 0; nt < 4; nt++)
                    acc[mt][nt] = __builtin_amdgcn_mfma_f32_16x16x32_bf16(ac[mt], bc[nt], acc[mt][nt], 0, 0, 0);

            #pragma unroll
            for (int mt = 0; mt < 4; mt++) ac[mt] = an[mt];
            #pragma unroll
            for (int nt = 0; nt < 4; nt++) bc[nt] = bn[nt];
        }
    }

    // ---- two-pass cross-wave reduction overlaid on patch (32 KB) ----
    __syncthreads();
    float* red = (float*)patch;
    if (wv >= 2) {
        #pragma unroll
        for (int mt = 0; mt < 4; mt++)
            #pragma unroll
            for (int nt = 0; nt < 4; nt++)
                *(f32x4*)(red + (wv - 2) * 4096 + (mt * 4 + nt) * 256 + lane * 4) = acc[mt][nt];
    }
    __syncthreads();
    if (wv < 2) {
        #pragma unroll
        for (int mt = 0; mt < 4; mt++)
            #pragma unroll
            for (int nt = 0; nt < 4; nt++) {
                acc[mt][nt] += *(const f32x4*)(red + wv * 4096 + (mt * 4 + nt) * 256 + lane * 4);
                *(f32x4*)(red + wv * 4096 + (mt * 4 + nt) * 256 + lane * 4) = acc[mt][nt];
            }
    }
    __syncthreads();

    // each wave stores its 4 frags: final = half0 + half1
    #pragma unroll
    for (int nt = 0; nt < 4; nt++) {
        int f = wv * 4 + nt;
        f32x4 s = *(const f32x4*)(red + f * 256 + lane * 4);
        s += *(const f32x4*)(red + 4096 + f * 256 + lane * 4);
        int zz = z0 + nt, yy = y0 + (n >> 2), xx = x0 + (n & 3);
        #pragma unroll
        for (int r = 0; r < 4; r++) {
            int o = wv * 16 + q * 4 + r;
            out[((o * OSD + zz) * OSD + yy) * OSD + xx] = s[r];
        }
    }
}

extern "C" void kernel_launch(void* const* d_in, const int* in_sizes, int n_in,
                              void* d_out, int out_size, void* d_ws, size_t ws_size,
                              hipStream_t stream) {
    const float* x      = (const float*)d_in[0];
    const float* weight = (const float*)d_in[1];
    const float* w_sc0  = (const float*)d_in[2];
    const float* w_sc1  = (const float*)d_in[3];
    float* out = (float*)d_out;

    ush* A  = (ush*)d_ws;                               // 514048 ush (incl. zero pad)
    ush* xb = (ush*)((char*)d_ws + (2 << 20));          // 22.5 MB

    build_A<<<(N_A_ELEMS + 2048) / 256, 256, 0, stream>>>(weight, w_sc0, w_sc1, A);
    dim3 gx(SP3 / 64, 2, 1);
    conv_x<<<gx, 256, 0, stream>>>(x, xb);
    dim3 grid(13, 13, 13);
    conv_main<<<grid, 256, 0, stream>>>(A, xb, out);
}

// Round 5
// 256.549 us; speedup vs baseline: 2.3988x; 1.0315x over previous
//
#include <hip/hip_runtime.h>
#include <hip/hip_bf16.h>

typedef unsigned short ush;
typedef __bf16 v8bf __attribute__((ext_vector_type(8)));
typedef float f32x4 __attribute__((ext_vector_type(4)));

#define SPD 56           // input spatial dim
#define OSD 52           // output spatial dim
#define SP3 175616       // 56^3
#define N_A_ELEMS (2*125*64*32)   // 512000 (+2048 zero pad appended)
#define NCX 5488         // conv_x blocks: 2744 spatial-chunks x 2 cg
#define NBA 2008         // build_A blocks: 514048/256

// ---------------- kernel 1: fused aux — conv_x transpose + build_A ---------------------
__global__ void aux_kernel(const float* __restrict__ x, ush* __restrict__ xb,
                           const float* __restrict__ weight, const float* __restrict__ w_sc0,
                           const float* __restrict__ w_sc1, ush* __restrict__ A) {
    __shared__ float t[64 * 33];
    const int bid = blockIdx.x;
    const int tid = threadIdx.x;
    if (bid < NCX) {
        // ---- conv_x: x fp32 [c64][s] -> bf16 [cg2][s][c32] via LDS transpose ----
        const int s0 = (bid % 2744) * 64;
        const int cg = bid / 2744;
        const int w = tid >> 6, l = tid & 63;
        #pragma unroll
        for (int k = 0; k < 8; k++) {
            int c = w * 8 + k;
            t[l * 33 + c] = x[(cg * 32 + c) * SP3 + s0 + l];
        }
        __syncthreads();
        int v = tid >> 2, qq = tid & 3;
        union { ush u[8]; uint4 q4; } pk;
        #pragma unroll
        for (int j = 0; j < 8; j++) {
            __hip_bfloat16 b = __float2bfloat16(t[v * 33 + qq * 8 + j]);
            pk.u[j] = *(ush*)&b;
        }
        *(uint4*)(xb + ((size_t)(cg * SP3 + s0 + v)) * 32 + qq * 8) = pk.q4;
        return;
    }
    // ---- build_A: A[cg][tau][o][c] bf16, zero slice at tap index 250 ----
    int f = (bid - NCX) * 256 + tid;
    if (f >= N_A_ELEMS) {
        if (f < N_A_ELEMS + 2048) A[f] = 0;
        return;
    }
    int c   = f & 31;
    int o   = (f >> 5) & 63;
    int t2  = f >> 11;
    int tau = t2 % 125;
    int cg  = t2 / 125;
    int i   = cg * 32 + c;
    int dz = tau / 25, dy = (tau / 5) % 5, dx = tau % 5;
    float rz = -1.f + 0.5f * dz, ry = -1.f + 0.5f * dy, rx = -1.f + 0.5f * dx;
    float d = sqrtf(rz * rz + ry * ry + rx * rx);
    float dm = fmaxf(d, 1e-12f);
    float nv[3] = { rz / dm, ry / dm, rx / dm };
    float emb[5];
    #pragma unroll
    for (int m = 0; m < 5; m++) {
        float diff = 4.f * d - (float)m;
        float ta = diff + 1.f, tb = 1.f - diff;
        float sa = ta > 0.f ? expf(-1.f / ta) : 0.f;
        float sb = tb > 0.f ? expf(-1.f / tb) : 0.f;
        emb[m] = 1.14136f * 7.3890560989306495f * sa * sb;
    }
    const float PW0 = 0.17677669529663687f;
    const float PW1 = 0.30618621784789724f;
    const float IS3 = 0.57735026918962576f;
    float val = 0.f;
    int widx = -1; float scale = 0.f;
    if (i < 16) {
        if (o < 16) { widx = i * 16 + o;                         scale = PW0; }
        else        { int wc = (o - 16) / 3, kc = (o - 16) % 3;
                      widx = 256 + i * 16 + wc;                  scale = PW1 * nv[kc]; }
    } else {
        int u = (i - 16) / 3, ic = (i - 16) % 3;
        if (o < 16) { widx = 768 + u * 16 + o;                   scale = PW0 * nv[ic]; }
        else        { int wc = (o - 16) / 3, jc = (o - 16) % 3;
                      if (ic == jc) { widx = 512 + u * 16 + wc;  scale = PW1 * IS3; } }
    }
    if (widx >= 0) {
        float wv = 0.f;
        #pragma unroll
        for (int m = 0; m < 5; m++) wv += emb[m] * weight[m * 1024 + widx];
        val = scale * wv;
    }
    if (tau == 62) {
        if (i < 16 && o < 16) val += 0.25f * w_sc0[i * 16 + o];
        else if (i >= 16 && o >= 16) {
            int u = (i - 16) / 3, ic = (i - 16) % 3;
            int wc = (o - 16) / 3, jc = (o - 16) % 3;
            if (ic == jc) val += 0.25f * w_sc1[u * 16 + wc];
        }
    }
    __hip_bfloat16 b = __float2bfloat16(val);
    A[f] = *(ush*)&b;
}

// ---------------- kernel 2: main conv ---------------------------------------------------
// grid (13,13,7); block 256 = 4 waves. Each wave: full 64oc x TWO 4x4x4 px tiles
// (z0, z0+4). K-split 128 taps (125 real + 3 zero-A) x 32/wave, A+B pipelined 1 ahead.
// patch: 12x8x8 vox x 32ch = 48 KB staged per cg (XOR-swizzled); 64 KB LDS for epilogue.
__launch_bounds__(256, 2)
__global__ void conv_main(const ush* __restrict__ A, const ush* __restrict__ xb,
                          float* __restrict__ out) {
    __shared__ ush patch[32768];   // 65536 B; staging uses 49152 B; reduction uses all

    const int tid  = threadIdx.x;
    const int wv   = tid >> 6;
    const int lane = tid & 63;
    const int n    = lane & 15;
    const int q    = lane >> 4;
    const int x0 = blockIdx.x * 4, y0 = blockIdx.y * 4, z0 = blockIdx.z * 8;
    const bool tile2_valid = (blockIdx.z < 6);

    // pixel p = nt*16 + n -> (z=nt, y=n>>2, x=n&3); patch voxel = zp*64 + yp*8 + xp
    const int rbase = ((n >> 2) << 3) + (n & 3);
    const ush* Aw = A + n * 32 + q * 8;

    f32x4 acc[4][8];
    #pragma unroll
    for (int mt = 0; mt < 4; mt++)
        #pragma unroll
        for (int u = 0; u < 8; u++) {
            f32x4 z = {0.f, 0.f, 0.f, 0.f};
            acc[mt][u] = z;
        }

    for (int cg = 0; cg < 2; cg++) {
        __syncthreads();
        // stage this cg: 768 vox x 32ch = 3072 16B-chunks, 12 per thread, swizzled
        #pragma unroll 4
        for (int it = 0; it < 12; it++) {
            int u   = tid + it * 256;
            int qq  = u & 3;
            int vox = u >> 2;
            int xp = vox & 7, yp = (vox >> 3) & 7, zp = vox >> 6;   // zp in [0,12)
            int zsrc = z0 + zp; if (zsrc > 55) zsrc = 55;            // clamp (bz=6 only)
            const ush* g = xb + ((size_t)((cg * SPD + zsrc) * SPD + (y0 + yp)) * SPD + (x0 + xp)) * 32 + qq * 8;
            uint4 v = *(const uint4*)g;
            int slot = vox * 4 + ((qq + vox + (vox >> 3)) & 3);
            *(uint4*)(patch + slot * 8) = v;
        }
        __syncthreads();

        // ---- K-split: wave wv owns taps [wv*32, wv*32+32); taps >=125 have zero A ----
        const int t0 = wv * 32;
        int dz = t0 / 25; int rr = t0 - dz * 25; int dy = rr / 5; int dx = rr - dy * 5;
        int vb = dz * 64 + dy * 8 + dx;
        int v0 = vb + rbase;
        int slot0 = v0 * 4 + ((q + v0 + (v0 >> 3)) & 3);

        v8bf bc[8], ac[4];
        #pragma unroll
        for (int tl = 0; tl < 2; tl++)
            #pragma unroll
            for (int nt = 0; nt < 4; nt++)
                bc[tl * 4 + nt] = *(const v8bf*)(patch + slot0 * 8 + nt * 2048 + tl * 8192);
        {
            int toff = cg * 125 + t0;
            #pragma unroll
            for (int mt = 0; mt < 4; mt++)
                ac[mt] = *(const v8bf*)(Aw + (size_t)toff * 2048 + mt * 512);
        }

        #pragma unroll 2
        for (int j = 0; j < 32; j++) {
            // advance decode to tap t0+j+1
            int c1 = (dx == 4);
            dx = c1 ? 0 : dx + 1;
            int c2 = c1 & (dy == 4);
            dy = c2 ? 0 : dy + c1;
            dz += c2;
            int vbn = dz * 64 + dy * 8 + dx;
            int vbs = (vbn > 292) ? 0 : vbn;          // clamp pad taps in-bounds
            int v1 = vbs + rbase;
            int slot1 = v1 * 4 + ((q + v1 + (v1 >> 3)) & 3);

            v8bf bn[8];
            #pragma unroll
            for (int tl = 0; tl < 2; tl++)
                #pragma unroll
                for (int nt = 0; nt < 4; nt++)
                    bn[tl * 4 + nt] = *(const v8bf*)(patch + slot1 * 8 + nt * 2048 + tl * 8192);

            int tn = t0 + j + 1;
            int toffn = (tn < 125) ? (cg * 125 + tn) : 250;   // 250 -> zero slice
            v8bf an[4];
            #pragma unroll
            for (int mt = 0; mt < 4; mt++)
                an[mt] = *(const v8bf*)(Aw + (size_t)toffn * 2048 + mt * 512);

            #pragma unroll
            for (int mt = 0; mt < 4; mt++)
                #pragma unroll
                for (int u = 0; u < 8; u++)
                    acc[mt][u] = __builtin_amdgcn_mfma_f32_16x16x32_bf16(ac[mt], bc[u], acc[mt][u], 0, 0, 0);

            #pragma unroll
            for (int mt = 0; mt < 4; mt++) ac[mt] = an[mt];
            #pragma unroll
            for (int u = 0; u < 8; u++) bc[u] = bn[u];
        }
    }

    // ---- single-pass cross-wave reduction: red[half][tile][frag16][lane][4] = 64 KB ----
    __syncthreads();
    float* red = (float*)patch;
    if (wv >= 2) {
        #pragma unroll
        for (int tl = 0; tl < 2; tl++)
            #pragma unroll
            for (int mt = 0; mt < 4; mt++)
                #pragma unroll
                for (int nt = 0; nt < 4; nt++)
                    *(f32x4*)(red + (((wv - 2) * 2 + tl) * 16 + mt * 4 + nt) * 256 + lane * 4) = acc[mt][tl * 4 + nt];
    }
    __syncthreads();
    if (wv < 2) {
        #pragma unroll
        for (int tl = 0; tl < 2; tl++)
            #pragma unroll
            for (int mt = 0; mt < 4; mt++)
                #pragma unroll
                for (int nt = 0; nt < 4; nt++) {
                    int idx = ((wv * 2 + tl) * 16 + mt * 4 + nt) * 256 + lane * 4;
                    f32x4 s = acc[mt][tl * 4 + nt] + *(const f32x4*)(red + idx);
                    *(f32x4*)(red + idx) = s;
                }
    }
    __syncthreads();

    // each wave stores mt = wv row for both tiles: final = half0 + half1
    #pragma unroll
    for (int tl = 0; tl < 2; tl++) {
        if (tl == 1 && !tile2_valid) break;
        #pragma unroll
        for (int nt = 0; nt < 4; nt++) {
            int f = wv * 4 + nt;
            f32x4 s = *(const f32x4*)(red + ((0 * 2 + tl) * 16 + f) * 256 + lane * 4);
            s += *(const f32x4*)(red + ((1 * 2 + tl) * 16 + f) * 256 + lane * 4);
            int zz = z0 + tl * 4 + nt, yy = y0 + (n >> 2), xx = x0 + (n & 3);
            #pragma unroll
            for (int r = 0; r < 4; r++) {
                int o = wv * 16 + q * 4 + r;
                out[((o * OSD + zz) * OSD + yy) * OSD + xx] = s[r];
            }
        }
    }
}

extern "C" void kernel_launch(void* const* d_in, const int* in_sizes, int n_in,
                              void* d_out, int out_size, void* d_ws, size_t ws_size,
                              hipStream_t stream) {
    const float* x      = (const float*)d_in[0];
    const float* weight = (const float*)d_in[1];
    const float* w_sc0  = (const float*)d_in[2];
    const float* w_sc1  = (const float*)d_in[3];
    float* out = (float*)d_out;

    ush* A  = (ush*)d_ws;                               // 514048 ush (incl. zero pad)
    ush* xb = (ush*)((char*)d_ws + (2 << 20));          // 22.5 MB

    aux_kernel<<<NCX + NBA, 256, 0, stream>>>(x, xb, weight, w_sc0, w_sc1, A);
    dim3 grid(13, 13, 7);
    conv_main<<<grid, 256, 0, stream>>>(A, xb, out);
}

// Round 6
// 231.716 us; speedup vs baseline: 2.6559x; 1.1072x over previous
//
#include <hip/hip_runtime.h>
#include <hip/hip_bf16.h>

typedef unsigned short ush;
typedef __bf16 v8bf __attribute__((ext_vector_type(8)));
typedef float f32x4 __attribute__((ext_vector_type(4)));
typedef float f32x16 __attribute__((ext_vector_type(16)));

#define SPD 56           // input spatial dim
#define OSD 52           // output spatial dim
#define SP3 175616       // 56^3
#define N_A_ELEMS (2*125*64*32)   // 512000 (+2048 zero pad appended)
#define NCX 5488         // conv_x blocks: 2744 spatial-chunks x 2 cg
#define NBA 2008         // build_A blocks: 514048/256

// ---------------- kernel 1: fused aux — conv_x transpose + build_A ---------------------
__global__ void aux_kernel(const float* __restrict__ x, ush* __restrict__ xb,
                           const float* __restrict__ weight, const float* __restrict__ w_sc0,
                           const float* __restrict__ w_sc1, ush* __restrict__ A) {
    __shared__ float t[64 * 33];
    const int bid = blockIdx.x;
    const int tid = threadIdx.x;
    if (bid < NCX) {
        // ---- conv_x: x fp32 [c64][s] -> bf16 [cg2][s][c32] via LDS transpose ----
        const int s0 = (bid % 2744) * 64;
        const int cg = bid / 2744;
        const int w = tid >> 6, l = tid & 63;
        #pragma unroll
        for (int k = 0; k < 8; k++) {
            int c = w * 8 + k;
            t[l * 33 + c] = x[(cg * 32 + c) * SP3 + s0 + l];
        }
        __syncthreads();
        int v = tid >> 2, qq = tid & 3;
        union { ush u[8]; uint4 q4; } pk;
        #pragma unroll
        for (int j = 0; j < 8; j++) {
            __hip_bfloat16 b = __float2bfloat16(t[v * 33 + qq * 8 + j]);
            pk.u[j] = *(ush*)&b;
        }
        *(uint4*)(xb + ((size_t)(cg * SP3 + s0 + v)) * 32 + qq * 8) = pk.q4;
        return;
    }
    // ---- build_A: A[cg][tau][o][c] bf16, zero slice at tap index 250 ----
    int f = (bid - NCX) * 256 + tid;
    if (f >= N_A_ELEMS) {
        if (f < N_A_ELEMS + 2048) A[f] = 0;
        return;
    }
    int c   = f & 31;
    int o   = (f >> 5) & 63;
    int t2  = f >> 11;
    int tau = t2 % 125;
    int cg  = t2 / 125;
    int i   = cg * 32 + c;
    int dz = tau / 25, dy = (tau / 5) % 5, dx = tau % 5;
    float rz = -1.f + 0.5f * dz, ry = -1.f + 0.5f * dy, rx = -1.f + 0.5f * dx;
    float d = sqrtf(rz * rz + ry * ry + rx * rx);
    float dm = fmaxf(d, 1e-12f);
    float nv[3] = { rz / dm, ry / dm, rx / dm };
    float emb[5];
    #pragma unroll
    for (int m = 0; m < 5; m++) {
        float diff = 4.f * d - (float)m;
        float ta = diff + 1.f, tb = 1.f - diff;
        float sa = ta > 0.f ? expf(-1.f / ta) : 0.f;
        float sb = tb > 0.f ? expf(-1.f / tb) : 0.f;
        emb[m] = 1.14136f * 7.3890560989306495f * sa * sb;
    }
    const float PW0 = 0.17677669529663687f;
    const float PW1 = 0.30618621784789724f;
    const float IS3 = 0.57735026918962576f;
    float val = 0.f;
    int widx = -1; float scale = 0.f;
    if (i < 16) {
        if (o < 16) { widx = i * 16 + o;                         scale = PW0; }
        else        { int wc = (o - 16) / 3, kc = (o - 16) % 3;
                      widx = 256 + i * 16 + wc;                  scale = PW1 * nv[kc]; }
    } else {
        int u = (i - 16) / 3, ic = (i - 16) % 3;
        if (o < 16) { widx = 768 + u * 16 + o;                   scale = PW0 * nv[ic]; }
        else        { int wc = (o - 16) / 3, jc = (o - 16) % 3;
                      if (ic == jc) { widx = 512 + u * 16 + wc;  scale = PW1 * IS3; } }
    }
    if (widx >= 0) {
        float wv = 0.f;
        #pragma unroll
        for (int m = 0; m < 5; m++) wv += emb[m] * weight[m * 1024 + widx];
        val = scale * wv;
    }
    if (tau == 62) {
        if (i < 16 && o < 16) val += 0.25f * w_sc0[i * 16 + o];
        else if (i >= 16 && o >= 16) {
            int u = (i - 16) / 3, ic = (i - 16) % 3;
            int wc = (o - 16) / 3, jc = (o - 16) % 3;
            if (ic == jc) val += 0.25f * w_sc1[u * 16 + wc];
        }
    }
    __hip_bfloat16 b = __float2bfloat16(val);
    A[f] = *(ush*)&b;
}

// ---------------- kernel 2: main conv ---------------------------------------------------
// 1184 blocks (flat, XCD-swizzled) = 13x13x7 tiles; block 256 = 4 waves.
// Each wave: 64 oc x 128 px (4 n-tiles of 32 px = 2 z-slices each), 32x32x16 MFMA.
// K-split 128 taps (125 real + 3 zero-A) x 32/wave; flat loop (compiler-scheduled).
// bz=6 overlaps z0=44 (rewrites z44..47 with identical values) -> no masking anywhere.
__launch_bounds__(256, 2)
__global__ void conv_main(const ush* __restrict__ A, const ush* __restrict__ xb,
                          float* __restrict__ out) {
    __shared__ ush patch[32768];   // 64 KB: staging 48 KB, epilogue red 64 KB

    const int b  = blockIdx.x;
    const int bp = (b & 7) * 148 + (b >> 3);   // XCD-contiguous slab mapping
    if (bp >= 1183) return;
    const int bx = bp % 13;
    const int t1 = bp / 13;
    const int by = t1 % 13;
    const int bz = t1 / 13;                    // 0..6
    const int x0 = bx * 4, y0 = by * 4;
    const int z0 = (bz == 6) ? 44 : bz * 8;

    const int tid  = threadIdx.x;
    const int wv   = tid >> 6;
    const int lane = tid & 63;
    const int lhi  = lane >> 5;                // k-group for A/B operands
    // B col = lane&31 -> px (zloc = (l>>4)&1, y = (l>>2)&3, x = l&3)
    const int rbase32 = ((lane >> 4) & 1) * 64 + ((lane >> 2) & 3) * 8 + (lane & 3);
    const ush* Aw = A + (lane & 31) * 32 + lhi * 8;

    f32x16 acc[2][4];
    #pragma unroll
    for (int mt = 0; mt < 2; mt++)
        #pragma unroll
        for (int nt = 0; nt < 4; nt++)
            acc[mt][nt] = (f32x16)(0.f);

    for (int cg = 0; cg < 2; cg++) {
        __syncthreads();
        // stage this cg: 12 z-slices x 64 vox x 32ch = 3072 16B-chunks, swizzled
        #pragma unroll 4
        for (int it = 0; it < 12; it++) {
            int u   = tid + it * 256;
            int qq  = u & 3;
            int vox = u >> 2;
            int xp = vox & 7, yp = (vox >> 3) & 7, zp = vox >> 6;   // zp in [0,12)
            const ush* g = xb + ((size_t)((cg * SPD + z0 + zp) * SPD + (y0 + yp)) * SPD + (x0 + xp)) * 32 + qq * 8;
            uint4 v = *(const uint4*)g;
            int slot = vox * 4 + ((qq + vox + (vox >> 3)) & 3);
            *(uint4*)(patch + slot * 8) = v;
        }
        __syncthreads();

        // ---- K-split: wave wv owns taps [wv*32, wv*32+32); taps >=125 are zero-A ----
        const int t0 = wv * 32;
        int dz = t0 / 25; int rr = t0 - dz * 25; int dy = rr / 5; int dx = rr - dy * 5;

        #pragma unroll 2
        for (int j = 0; j < 32; j++) {
            int t = t0 + j;
            int vb = dz * 64 + dy * 8 + dx;
            if (vb > 292) vb = 0;                          // pad taps stay in-bounds
            int v0 = vb + rbase32;
            int pre = v0 + (v0 >> 3);
            int slot0 = v0 * 4 + ((lhi + pre) & 3);        // chunk h=0
            int slot1 = v0 * 4 + ((2 + lhi + pre) & 3);    // chunk h=1

            v8bf bf[4][2];
            #pragma unroll
            for (int nt = 0; nt < 4; nt++) {
                bf[nt][0] = *(const v8bf*)(patch + slot0 * 8 + nt * 4096);
                bf[nt][1] = *(const v8bf*)(patch + slot1 * 8 + nt * 4096);
            }

            int toff = (t < 125) ? (cg * 125 + t) : 250;   // 250 -> zero slice
            v8bf af[2][2];
            #pragma unroll
            for (int mt = 0; mt < 2; mt++)
                #pragma unroll
                for (int h = 0; h < 2; h++)
                    af[mt][h] = *(const v8bf*)(Aw + (size_t)toff * 2048 + mt * 1024 + h * 16);

            #pragma unroll
            for (int h = 0; h < 2; h++)
                #pragma unroll
                for (int mt = 0; mt < 2; mt++)
                    #pragma unroll
                    for (int nt = 0; nt < 4; nt++)
                        acc[mt][nt] = __builtin_amdgcn_mfma_f32_32x32x16_bf16(af[mt][h], bf[nt][h], acc[mt][nt], 0, 0, 0);

            int c1 = (dx == 4);
            dx = c1 ? 0 : dx + 1;
            int c2 = c1 & (dy == 4);
            dy = c2 ? 0 : dy + c1;
            dz += c2;
        }
    }

    // ---- cross-wave reduction: red[writer][frag8][lane][16] = 64 KB ----
    __syncthreads();
    float* red = (float*)patch;
    if (wv >= 2) {
        #pragma unroll
        for (int mt = 0; mt < 2; mt++)
            #pragma unroll
            for (int nt = 0; nt < 4; nt++) {
                float* p = red + (wv - 2) * 8192 + (mt * 4 + nt) * 1024 + lane * 16;
                #pragma unroll
                for (int s = 0; s < 4; s++) {
                    f32x4 v = { acc[mt][nt][s*4+0], acc[mt][nt][s*4+1], acc[mt][nt][s*4+2], acc[mt][nt][s*4+3] };
                    *(f32x4*)(p + s * 4) = v;
                }
            }
    }
    __syncthreads();
    if (wv < 2) {
        #pragma unroll
        for (int mt = 0; mt < 2; mt++)
            #pragma unroll
            for (int nt = 0; nt < 4; nt++) {
                float* p = red + wv * 8192 + (mt * 4 + nt) * 1024 + lane * 16;
                #pragma unroll
                for (int s = 0; s < 4; s++) {
                    f32x4 v = *(const f32x4*)(p + s * 4);
                    f32x4 m = { acc[mt][nt][s*4+0], acc[mt][nt][s*4+1], acc[mt][nt][s*4+2], acc[mt][nt][s*4+3] };
                    *(f32x4*)(p + s * 4) = v + m;
                }
            }
    }
    __syncthreads();

    // store: 8 frags total; wave wv stores frags {2wv, 2wv+1}; final = half0 + half1
    const int yy = y0 + ((lane >> 2) & 3);
    const int xx = x0 + (lane & 3);
    #pragma unroll
    for (int k = 0; k < 2; k++) {
        int fi = wv * 2 + k;
        int mt = fi >> 2, nt = fi & 3;
        int zz = z0 + nt * 2 + ((lane >> 4) & 1);
        #pragma unroll
        for (int s = 0; s < 4; s++) {
            f32x4 v = *(const f32x4*)(red + fi * 1024 + lane * 16 + s * 4);
            v += *(const f32x4*)(red + 8192 + fi * 1024 + lane * 16 + s * 4);
            #pragma unroll
            for (int e = 0; e < 4; e++) {
                int o = mt * 32 + e + 8 * s + 4 * lhi;
                out[((o * OSD + zz) * OSD + yy) * OSD + xx] = v[e];
            }
        }
    }
}

extern "C" void kernel_launch(void* const* d_in, const int* in_sizes, int n_in,
                              void* d_out, int out_size, void* d_ws, size_t ws_size,
                              hipStream_t stream) {
    const float* x      = (const float*)d_in[0];
    const float* weight = (const float*)d_in[1];
    const float* w_sc0  = (const float*)d_in[2];
    const float* w_sc1  = (const float*)d_in[3];
    float* out = (float*)d_out;

    ush* A  = (ush*)d_ws;                               // 514048 ush (incl. zero pad)
    ush* xb = (ush*)((char*)d_ws + (2 << 20));          // 22.5 MB

    aux_kernel<<<NCX + NBA, 256, 0, stream>>>(x, xb, weight, w_sc0, w_sc1, A);
    conv_main<<<1184, 256, 0, stream>>>(A, xb, out);
}